// Round 3
// baseline (1889.817 us; speedup 1.0000x reference)
//
#include <hip/hip_runtime.h>
#include <stdint.h>

#define BB 32
#define CIN 128
#define COUT 256
#define HH 64
#define WW 64
#define TOPK 64
#define NS_D (8.0/255.0)

#define A_STRIDE 96    // doubles per A row (8 granules of 10 @ 12g + 2*(g>>2) — disjoint)
#define B_STRIDE 256   // doubles per B row (XOR-swizzled double2 units, bijective)
#define EPI_STRIDE 258 // doubles per epilogue pos-row (256 ch + pad)

// ---------------- prep: absw[c] (fp64) = sum|w[c]|, wT[(kh*3+kw)][ci][c] = w[c][ci][kh][kw] (fp32)
__global__ __launch_bounds__(256) void prep_kernel(const float* __restrict__ w,
                                                   double* __restrict__ absw,
                                                   float* __restrict__ wT) {
    const int c = blockIdx.x;
    const int t = threadIdx.x;
    double s = 0.0;
    for (int k = t; k < CIN * 9; k += 256) {
        float v = w[c * (CIN * 9) + k];
        s += fabs((double)v);
        int ci = k / 9;
        int r  = k % 9;
        wT[(r * CIN + ci) * COUT + c] = v;
    }
    __shared__ double red[4];
    for (int m = 32; m; m >>= 1) s += __shfl_xor(s, m, 64);
    if ((t & 63) == 0) red[t >> 6] = s;
    __syncthreads();
    if (t == 0) absw[c] = red[0] + red[1] + red[2] + red[3];
}

// ---------------- fused conv(fp64 acc) + noise(fp64) + exact fp64 topk-threshold + bias-relu
__global__ __launch_bounds__(256, 2) void fused_kernel(
    const float* __restrict__ x,
    const float* __restrict__ relu_bias,
    const float* __restrict__ noise,
    const double* __restrict__ absw,
    const float* __restrict__ wT,
    float* __restrict__ out) {

    __shared__ alignas(16) union {
        struct { double a[8 * A_STRIDE]; double b[24 * B_STRIDE]; } conv; // 6144B + 49152B
        struct { double o[16 * EPI_STRIDE]; } epi;                        // 33024B
    } U;
    __shared__ double lds_absw[COUT];
    __shared__ double lds_bias[COUT];
    __shared__ double thr[16];

    const int tid = threadIdx.x;
    const int b = blockIdx.x >> 6;
    const int h = blockIdx.x & 63;

    const int tw = tid & 7;   // position group: p = tw*8 + i
    const int tc = tid >> 3;  // channel group: c = tc*8 + j   (0..31)

    lds_absw[tid] = absw[tid];
    lds_bias[tid] = (double)relu_bias[tid];

    double acc[8][8];
#pragma unroll
    for (int i = 0; i < 8; ++i)
#pragma unroll
        for (int j = 0; j < 8; ++j) acc[i][j] = 0.0;

    const int aoff = 12 * tw + 2 * (tw >> 2);  // staggered A granule start (disjoint)

    // B read offsets: channel granule tc holds double2 units u=4*tc+m at swizzled
    // slot (u ^ ((u>>3)&7)); (4*tc+m)>>3 == tc>>1 for m in [0,4).
    int bo[4];
    {
        const int kk = (tc >> 1) & 7;
#pragma unroll
        for (int m = 0; m < 4; ++m) bo[m] = ((4 * tc + m) ^ kk) * 2;
    }

    // ---------- GEMM: K = (kh, ci, kw), fp64 accumulate
    for (int kh = 0; kh < 3; ++kh) {
        const int r = h + kh - 1;
        if (r < 0 || r >= HH) continue;  // uniform per block
        for (int cib = 0; cib < CIN; cib += 8) {
            __syncthreads();
            // stage A: replicated per-position-granule, fp32->fp64
            // granule g holds w = 8g-1 .. 8g+8 (10 slots) at double-off 12g + 2*(g>>2)
#pragma unroll
            for (int pass = 0; pass < 3; ++pass) {
                int slot = pass * 256 + tid;
                if (slot < 640) {
                    int row = slot / 80;
                    int rem = slot % 80;
                    int g = rem / 10, k = rem % 10;
                    int w = g * 8 - 1 + k;
                    float v = (w >= 0 && w < WW)
                        ? x[(((size_t)(b * CIN + cib + row) * HH + r) * WW) + w] : 0.f;
                    U.conv.a[row * A_STRIDE + 12 * g + 2 * (g >> 2) + k] = (double)v;
                }
            }
            // stage B: wT[(kh*3+kw)][cib+ci_l][c] -> fp64, XOR-swizzled double2 units
            {
                int t6 = tid & 63;
                int c4 = t6 * 4;
                int u0 = t6 * 2;            // double2 unit index (channels c4..c4+1)
                int k  = (u0 >> 3) & 7;     // same for u0 and u0+1
                int o0 = (u0 ^ k) * 2;      // double offset of unit u0
                int o1 = ((u0 + 1) ^ k) * 2;
                int rg = tid >> 6;
#pragma unroll
                for (int j = 0; j < 6; ++j) {
                    int row = rg + 4 * j;       // 0..23 == ci_l*3 + kw
                    int ci_l = row / 3, kw = row % 3;
                    float4 v = *(const float4*)&wT[((size_t)(kh * 3 + kw) * CIN + cib + ci_l) * COUT + c4];
                    double2 d0 = { (double)v.x, (double)v.y };
                    double2 d1 = { (double)v.z, (double)v.w };
                    *(double2*)&U.conv.b[row * B_STRIDE + o0] = d0;
                    *(double2*)&U.conv.b[row * B_STRIDE + o1] = d1;
                }
            }
            __syncthreads();
#pragma unroll
            for (int ci_l = 0; ci_l < 8; ++ci_l) {
                double win[10];
                const double* arow = &U.conv.a[ci_l * A_STRIDE + aoff];
#pragma unroll
                for (int q = 0; q < 5; ++q)
                    *(double2*)&win[2 * q] = *(const double2*)&arow[2 * q];
#pragma unroll
                for (int kw = 0; kw < 3; ++kw) {
                    double bw[8];
                    const double* brow = &U.conv.b[(ci_l * 3 + kw) * B_STRIDE];
#pragma unroll
                    for (int m = 0; m < 4; ++m)
                        *(double2*)&bw[2 * m] = *(const double2*)&brow[bo[m]];
#pragma unroll
                    for (int i = 0; i < 8; ++i)
#pragma unroll
                        for (int j = 0; j < 8; ++j)
                            acc[i][j] = fma(win[i + kw], bw[j], acc[i][j]);
                }
            }
        }
    }

    // ---------- epilogue: four 16-position passes, all fp64 through the threshold
    for (int q = 0; q < 4; ++q) {
        __syncthreads();
        // phase 1: scatter acc -> U.epi.o[pos_local][ch]
        if ((tw >> 1) == q) {
            int pl0 = (tw & 1) * 8;
#pragma unroll
            for (int i = 0; i < 8; ++i)
#pragma unroll
                for (int m = 0; m < 4; ++m) {
                    double2 d = { acc[i][2 * m], acc[i][2 * m + 1] };
                    *(double2*)&U.epi.o[(pl0 + i) * EPI_STRIDE + tc * 8 + 2 * m] = d;
                }
        }
        __syncthreads();
        // phase 2: add noise (fp64)
        {
            int wl = tid & 15;
            int cg = tid >> 4;  // 0..15
            int wg = q * 16 + wl;
#pragma unroll 4
            for (int it = 0; it < 16; ++it) {
                int c = cg + 16 * it;
                double u = (double)noise[((size_t)(b * COUT + c) * HH + h) * WW + wg];
                U.epi.o[wl * EPI_STRIDE + c] += lds_absw[c] * NS_D * (2.0 * u - 1.0);
            }
        }
        __syncthreads();
        // phase 3: exact 64th-largest per position, radix descent on 64-bit sortable keys
        {
            int wave = tid >> 6;
            int lane = tid & 63;
#pragma unroll 1
            for (int pp = 0; pp < 4; ++pp) {
                int pl = wave * 4 + pp;  // 0..15
                uint64_t u[4];
#pragma unroll
                for (int j = 0; j < 4; ++j) {
                    double v = U.epi.o[pl * EPI_STRIDE + lane + 64 * j];
                    uint64_t bb = (uint64_t)__double_as_longlong(v);
                    u[j] = (bb & 0x8000000000000000ULL) ? ~bb : (bb | 0x8000000000000000ULL);
                }
                uint64_t prefix = 0;
                for (int bit = 63; bit >= 0; --bit) {
                    uint64_t cand = prefix | (1ULL << bit);
                    int cnt = (u[0] >= cand) + (u[1] >= cand) + (u[2] >= cand) + (u[3] >= cand);
                    for (int m = 1; m < 64; m <<= 1) cnt += __shfl_xor(cnt, m, 64);
                    if (cnt >= TOPK) {
                        prefix = cand;
                        if (cnt == TOPK) break;
                    }
                }
                uint64_t mn = ~0ULL;
#pragma unroll
                for (int j = 0; j < 4; ++j)
                    if (u[j] >= prefix) mn = (u[j] < mn) ? u[j] : mn;
                for (int m = 1; m < 64; m <<= 1) {
                    uint64_t o = (uint64_t)__shfl_xor((unsigned long long)mn, m, 64);
                    mn = (o < mn) ? o : mn;
                }
                if (lane == 0) {
                    uint64_t fb = (mn & 0x8000000000000000ULL) ? (mn & 0x7FFFFFFFFFFFFFFFULL) : ~mn;
                    thr[pl] = __longlong_as_double((long long)fb);
                }
            }
        }
        __syncthreads();
        // phase 4: threshold (>=), +bias, relu, cast to fp32, store
        {
            int wl = tid & 15;
            int cg = tid >> 4;
            int wg = q * 16 + wl;
            double tf = thr[wl];
#pragma unroll 4
            for (int it = 0; it < 16; ++it) {
                int c = cg + 16 * it;
                double v = U.epi.o[wl * EPI_STRIDE + c];
                double o = (v >= tf ? v : 0.0) + lds_bias[c];
                out[((size_t)(b * COUT + c) * HH + h) * WW + wg] = (float)fmax(o, 0.0);
            }
        }
    }
}

extern "C" void kernel_launch(void* const* d_in, const int* in_sizes, int n_in,
                              void* d_out, int out_size, void* d_ws, size_t ws_size,
                              hipStream_t stream) {
    const float* x         = (const float*)d_in[0];
    const float* weight    = (const float*)d_in[1];
    const float* relu_bias = (const float*)d_in[2];
    const float* noise_u   = (const float*)d_in[3];
    float* out = (float*)d_out;

    double* absw = (double*)d_ws;               // 256 doubles (2 KB)
    float*  wT   = (float*)(absw + COUT);       // 3*3*128*256 floats

    prep_kernel<<<COUT, 256, 0, stream>>>(weight, absw, wT);
    fused_kernel<<<BB * HH, 256, 0, stream>>>(x, relu_bias, noise_u, absw, wT, out);
}

// Round 4
// 1823.175 us; speedup vs baseline: 1.0366x; 1.0366x over previous
//
#include <hip/hip_runtime.h>
#include <stdint.h>

#define BB 32
#define CIN 128
#define COUT 256
#define HH 64
#define WW 64
#define TOPK 64
#define NS_D (8.0/255.0)
#define GAP 5e-4          // ambiguity band: ~33x the max fp32 accumulation error
#define EPI_STRIDE 258    // doubles per epilogue pos-row (256 ch + pad)
#define LIST_CAP 65536

__device__ __forceinline__ uint64_t sortkey(double v) {
    uint64_t b = (uint64_t)__double_as_longlong(v);
    return (b & 0x8000000000000000ULL) ? ~b : (b | 0x8000000000000000ULL);
}
__device__ __forceinline__ double unsortkey(uint64_t k) {
    uint64_t b = (k & 0x8000000000000000ULL) ? (k & 0x7FFFFFFFFFFFFFFFULL) : ~k;
    return __longlong_as_double((long long)b);
}

// per-wave exact select: lane holds u[0..3] (256 keys total). Returns 64th and
// 65th largest keys to ALL lanes.
__device__ __forceinline__ void select64(const uint64_t u[4], uint64_t& k64, uint64_t& k65) {
    uint64_t prefix = 0;
    for (int bit = 63; bit >= 0; --bit) {
        uint64_t cand = prefix | (1ULL << bit);
        int cnt = (u[0] >= cand) + (u[1] >= cand) + (u[2] >= cand) + (u[3] >= cand);
        for (int m = 1; m < 64; m <<= 1) cnt += __shfl_xor(cnt, m, 64);
        if (cnt >= TOPK) {
            prefix = cand;
            if (cnt == TOPK) break;
        }
    }
    uint64_t mn = ~0ULL, mx = 0ULL;
#pragma unroll
    for (int j = 0; j < 4; ++j) {
        if (u[j] >= prefix) { if (u[j] < mn) mn = u[j]; }
        else                { if (u[j] > mx) mx = u[j]; }
    }
    for (int m = 1; m < 64; m <<= 1) {
        uint64_t a = (uint64_t)__shfl_xor((unsigned long long)mn, m, 64);
        if (a < mn) mn = a;
        uint64_t b = (uint64_t)__shfl_xor((unsigned long long)mx, m, 64);
        if (b > mx) mx = b;
    }
    k64 = mn; k65 = mx;
}

// ---------------- prep: absw[c] (fp64), wT[(kh*3+kw)][ci][c] (fp32), zero flag counter
__global__ __launch_bounds__(256) void prep_kernel(const float* __restrict__ w,
                                                   double* __restrict__ absw,
                                                   float* __restrict__ wT,
                                                   int* __restrict__ counter) {
    const int c = blockIdx.x;
    const int t = threadIdx.x;
    if (c == 0 && t == 0) counter[0] = 0;
    double s = 0.0;
    for (int k = t; k < CIN * 9; k += 256) {
        float v = w[c * (CIN * 9) + k];
        s += fabs((double)v);
        int ci = k / 9;
        int r  = k % 9;
        wT[(r * CIN + ci) * COUT + c] = v;
    }
    __shared__ double red[4];
    for (int m = 32; m; m >>= 1) s += __shfl_xor(s, m, 64);
    if ((t & 63) == 0) red[t >> 6] = s;
    __syncthreads();
    if (t == 0) absw[c] = red[0] + red[1] + red[2] + red[3];
}

// ---------------- fused: fp32 conv + fp64-promoted epilogue + ambiguity flagging
__global__ __launch_bounds__(256, 4) void fused_kernel(
    const float* __restrict__ x,
    const float* __restrict__ relu_bias,
    const float* __restrict__ noise,
    const double* __restrict__ absw,
    const float* __restrict__ wT,
    float* __restrict__ out,
    int* __restrict__ counter,
    int* __restrict__ list) {

    __shared__ alignas(16) union {
        struct { float a[8 * 68]; float b[24 * 256]; } conv;  // 2176B + 24576B
        struct { double o[16 * EPI_STRIDE]; } epi;            // 33024B
    } U;
    __shared__ double lds_absw[COUT];
    __shared__ double lds_bias[COUT];
    __shared__ double thr[16];

    const int tid = threadIdx.x;
    const int b = blockIdx.x >> 6;
    const int h = blockIdx.x & 63;

    const int tw = tid & 7;   // position group: p = tw*8 + i
    const int tc = tid >> 3;  // channel group: c = tc*8 + j   (0..31)

    lds_absw[tid] = absw[tid];
    lds_bias[tid] = (double)relu_bias[tid];

    float acc[8][8];
#pragma unroll
    for (int i = 0; i < 8; ++i)
#pragma unroll
        for (int j = 0; j < 8; ++j) acc[i][j] = 0.f;

    // ---------- fp32 GEMM: K = (kh, ci, kw)
    for (int kh = 0; kh < 3; ++kh) {
        const int r = h + kh - 1;
        if (r < 0 || r >= HH) continue;  // uniform per block
        for (int cib = 0; cib < CIN; cib += 8) {
            __syncthreads();
            // stage A: x[b, cib..cib+7, r, 0..63] with halo zeros
            {
                int ci_l = tid >> 5;          // 0..7
                int w2 = (tid & 31) * 2;      // 0..62
                const float* xp = x + (((size_t)(b * CIN + cib + ci_l) * HH + r) * WW) + w2;
                float2 v = *(const float2*)xp;
                U.conv.a[ci_l * 68 + 1 + w2] = v.x;
                U.conv.a[ci_l * 68 + 2 + w2] = v.y;
                if ((tid & 31) == 0) { U.conv.a[ci_l * 68 + 0] = 0.f; U.conv.a[ci_l * 68 + 65] = 0.f; }
            }
            // stage B: wT[(kh*3+kw)][cib+ci_l][0..255] -> U.conv.b[(ci_l*3+kw)*256 + c]
            {
                int c4 = (tid & 63) * 4;
                int rg = tid >> 6;  // 0..3
#pragma unroll
                for (int j = 0; j < 6; ++j) {
                    int row = rg + 4 * j;       // 0..23 == ci_l*3 + kw
                    int ci_l = row / 3, kw = row % 3;
                    float4 v = *(const float4*)&wT[((size_t)(kh * 3 + kw) * CIN + cib + ci_l) * COUT + c4];
                    *(float4*)&U.conv.b[row * 256 + c4] = v;
                }
            }
            __syncthreads();
#pragma unroll
            for (int ci_l = 0; ci_l < 8; ++ci_l) {
                float win[12];
#pragma unroll
                for (int q = 0; q < 3; ++q)
                    *(float4*)&win[q * 4] = *(const float4*)&U.conv.a[ci_l * 68 + tw * 8 + q * 4];
                float bw[3][8];
#pragma unroll
                for (int kw = 0; kw < 3; ++kw) {
                    *(float4*)&bw[kw][0] = *(const float4*)&U.conv.b[(ci_l * 3 + kw) * 256 + tc * 8];
                    *(float4*)&bw[kw][4] = *(const float4*)&U.conv.b[(ci_l * 3 + kw) * 256 + tc * 8 + 4];
                }
#pragma unroll
                for (int kw = 0; kw < 3; ++kw)
#pragma unroll
                    for (int i = 0; i < 8; ++i)
#pragma unroll
                        for (int j = 0; j < 8; ++j)
                            acc[i][j] = fmaf(win[i + kw], bw[kw][j], acc[i][j]);
            }
        }
    }

    // ---------- epilogue: four 16-position passes, fp64 from here on
    for (int q = 0; q < 4; ++q) {
        __syncthreads();
        // phase 1: scatter promoted acc -> U.epi.o[pos_local][ch]
        if ((tw >> 1) == q) {
            int pl0 = (tw & 1) * 8;
#pragma unroll
            for (int i = 0; i < 8; ++i)
#pragma unroll
                for (int m = 0; m < 4; ++m) {
                    double2 d = { (double)acc[i][2 * m], (double)acc[i][2 * m + 1] };
                    *(double2*)&U.epi.o[(pl0 + i) * EPI_STRIDE + tc * 8 + 2 * m] = d;
                }
        }
        __syncthreads();
        // phase 2: add noise (fp64)
        {
            int wl = tid & 15;
            int cg = tid >> 4;  // 0..15
            int wg = q * 16 + wl;
#pragma unroll 4
            for (int it = 0; it < 16; ++it) {
                int c = cg + 16 * it;
                double u = (double)noise[((size_t)(b * COUT + c) * HH + h) * WW + wg];
                U.epi.o[wl * EPI_STRIDE + c] += lds_absw[c] * NS_D * (2.0 * u - 1.0);
            }
        }
        __syncthreads();
        // phase 3: exact 64th/65th per position; flag ambiguous pixels
        {
            int wave = tid >> 6;
            int lane = tid & 63;
#pragma unroll 1
            for (int pp = 0; pp < 4; ++pp) {
                int pl = wave * 4 + pp;  // 0..15
                uint64_t u[4];
#pragma unroll
                for (int j = 0; j < 4; ++j)
                    u[j] = sortkey(U.epi.o[pl * EPI_STRIDE + lane + 64 * j]);
                uint64_t k64, k65;
                select64(u, k64, k65);
                if (lane == 0) {
                    double t64 = unsortkey(k64);
                    thr[pl] = t64;
                    if (t64 - unsortkey(k65) < GAP) {
                        int idx = atomicAdd(counter, 1);
                        if (idx < LIST_CAP) list[idx] = (b << 12) | (h << 6) | (q * 16 + pl);
                    }
                }
            }
        }
        __syncthreads();
        // phase 4: threshold (>=), +bias, relu, cast to fp32, store
        {
            int wl = tid & 15;
            int cg = tid >> 4;
            int wg = q * 16 + wl;
            double tf = thr[wl];
#pragma unroll 4
            for (int it = 0; it < 16; ++it) {
                int c = cg + 16 * it;
                double v = U.epi.o[wl * EPI_STRIDE + c];
                double o = (v >= tf ? v : 0.0) + lds_bias[c];
                out[((size_t)(b * COUT + c) * HH + h) * WW + wg] = (float)fmax(o, 0.0);
            }
        }
    }
}

// ---------------- fixup: exact fp64 recompute of flagged pixels (whole pixel)
__global__ __launch_bounds__(256, 4) void fixup_kernel(
    const float* __restrict__ x,
    const float* __restrict__ w,      // original layout [c][ci][3][3]
    const float* __restrict__ relu_bias,
    const float* __restrict__ noise,
    const double* __restrict__ absw,
    float* __restrict__ out,
    const int* __restrict__ counter,
    const int* __restrict__ list) {

    __shared__ double xs[CIN * 9];    // 9216 B: patch [ci][kh*3+kw]
    __shared__ uint64_t keys[COUT];

    int n = counter[0];
    if (n > LIST_CAP) n = LIST_CAP;

    for (int it = blockIdx.x; it < n; it += gridDim.x) {
        int p = list[it];
        int b = p >> 12, h = (p >> 6) & 63, wg = p & 63;
        __syncthreads();
        for (int t = threadIdx.x; t < CIN * 9; t += 256) {
            int ci = t / 9, r = t % 9, kh = r / 3, kw = r % 3;
            int hh = h + kh - 1, ww = wg + kw - 1;
            xs[t] = (hh >= 0 && hh < HH && ww >= 0 && ww < WW)
                ? (double)x[(((size_t)(b * CIN + ci) * HH + hh) * WW) + ww] : 0.0;
        }
        __syncthreads();
        const int c = threadIdx.x;
        const float* wp = w + (size_t)c * (CIN * 9);
        double s = 0.0;
#pragma unroll 4
        for (int k = 0; k < CIN * 9; k += 4) {
            float4 wv = *(const float4*)&wp[k];
            s = fma((double)wv.x, xs[k],     s);
            s = fma((double)wv.y, xs[k + 1], s);
            s = fma((double)wv.z, xs[k + 2], s);
            s = fma((double)wv.w, xs[k + 3], s);
        }
        double u = (double)noise[(((size_t)(b * COUT + c) * HH + h) * WW) + wg];
        s += absw[c] * NS_D * (2.0 * u - 1.0);
        keys[c] = sortkey(s);
        __syncthreads();
        uint64_t uu[4];
        int lane = threadIdx.x & 63;
#pragma unroll
        for (int j = 0; j < 4; ++j) uu[j] = keys[lane + 64 * j];
        uint64_t k64, k65;
        select64(uu, k64, k65);   // all 4 waves compute identically
        double t64 = unsortkey(k64);
        double o = (s >= t64 ? s : 0.0) + (double)relu_bias[c];
        out[(((size_t)(b * COUT + c) * HH + h) * WW) + wg] = (float)fmax(o, 0.0);
    }
}

extern "C" void kernel_launch(void* const* d_in, const int* in_sizes, int n_in,
                              void* d_out, int out_size, void* d_ws, size_t ws_size,
                              hipStream_t stream) {
    const float* x         = (const float*)d_in[0];
    const float* weight    = (const float*)d_in[1];
    const float* relu_bias = (const float*)d_in[2];
    const float* noise_u   = (const float*)d_in[3];
    float* out = (float*)d_out;

    char* ws = (char*)d_ws;
    double* absw  = (double*)ws;                              // 2 KB
    float*  wT    = (float*)(ws + 2048);                      // 1,179,648 B
    int*    cnt   = (int*)(ws + 2048 + 1179648);              // 16 B slot
    int*    list  = (int*)(ws + 2048 + 1179648 + 16);         // 256 KB

    prep_kernel<<<COUT, 256, 0, stream>>>(weight, absw, wT, cnt);
    fused_kernel<<<BB * HH, 256, 0, stream>>>(x, relu_bias, noise_u, absw, wT, out, cnt, list);
    fixup_kernel<<<256, 256, 0, stream>>>(x, weight, relu_bias, noise_u, absw, out, cnt, list);
}